// Round 4
// baseline (289.094 us; speedup 1.0000x reference)
//
#include <hip/hip_runtime.h>
#include <cstdint>

// B=4, L=2048, H=512, HEADS=8, D=64.
// Only the DIAGONAL of softmax(scores) is consumed:
//   diag_i = exp(s_ii) / sum_j exp(s_ij),
//   s_ij = q_i.k_j + q_i.Wp[2047+j-i] + Wp_b[2047+j-i]
// Logits in log2 units (q pre-scaled by log2e/8, bias by log2e) -> one
// v_exp_f32 per element.  P (pos logits incl. bias) is precomputed by a
// band-compressed GEMM into Pb[rowL][c], c = 63 + j - (i - i0tile), width 2112
// (c <= 2110).  Done in TWO half-batch passes (bh 0..15, 16..31) so Pb is
// 4096x2112 bf16 = 17.3 MB; peak workspace 53.5 MB (Round-3's 74 MB faulted).
// The attention j-loop has NO barrier and NO LDS: 4 MFMA + 16 coalesced u16
// gathers + 16 exp2 per wave-iteration.

typedef unsigned short u16;
typedef __bf16 bf16x8 __attribute__((ext_vector_type(8)));
typedef float  f32x16 __attribute__((ext_vector_type(16)));
typedef uint32_t __attribute__((address_space(1))) as1_u32;
typedef uint32_t __attribute__((address_space(3))) as3_u32;

__device__ __forceinline__ u16 f2bf(float f) {
  uint32_t x = __float_as_uint(f);
  x += 0x7fffu + ((x >> 16) & 1u);   // RTNE (finite inputs)
  return (u16)(x >> 16);
}
__device__ __forceinline__ float bf2f(u16 u) {
  return __uint_as_float(((uint32_t)u) << 16);
}
__device__ __forceinline__ void gl_lds16(const void* g, void* l) {
  __builtin_amdgcn_global_load_lds((const as1_u32*)g, (as3_u32*)l, 16, 0, 0);
}

// ---------------------------------------------------------------------------
// Prep: fp32 -> bf16 for q/k/v inputs, Wq/Wk/Wv/Wo, Wp (padded to 4352 rows),
// plus wpb2[4352] = Wp_b * log2e (fp32, zero-padded).
// ---------------------------------------------------------------------------
__global__ __launch_bounds__(256) void prep_kernel(
    const float* __restrict__ qin, const float* __restrict__ kin, const float* __restrict__ vin,
    const float* __restrict__ wq,  const float* __restrict__ wk,  const float* __restrict__ wv,
    const float* __restrict__ wo,  const float* __restrict__ wp,  const float* __restrict__ wpb,
    u16* __restrict__ xq, u16* __restrict__ xk, u16* __restrict__ xv,
    u16* __restrict__ bwq, u16* __restrict__ bwk, u16* __restrict__ bwv,
    u16* __restrict__ bwo, u16* __restrict__ bwp, float* __restrict__ wpb2) {
  long u = (long)blockIdx.x * 256 + threadIdx.x;
  const float* src; u16* dst; long off;
  if      (u < 524288L)  { src = qin; dst = xq;  off = u; }
  else if (u < 1048576L) { src = kin; dst = xk;  off = u - 524288L; }
  else if (u < 1572864L) { src = vin; dst = xv;  off = u - 1048576L; }
  else if (u < 1605632L) { src = wq;  dst = bwq; off = u - 1572864L; }
  else if (u < 1638400L) { src = wk;  dst = bwk; off = u - 1605632L; }
  else if (u < 1671168L) { src = wv;  dst = bwv; off = u - 1638400L; }
  else if (u < 1703936L) { src = wo;  dst = bwo; off = u - 1671168L; }
  else if (u < 1736696L) { src = wp;  dst = bwp; off = u - 1703936L; }
  else if (u < 1738752L) {  // zero-fill Wp pad rows 4095..4351
    long o = (u - 1736696L) * 8 + 262080L;
    uint4 z = {0u, 0u, 0u, 0u};
    *(uint4*)(bwp + o) = z;
    return;
  } else if (u < 1739296L) {  // wpb2 = wpb * log2e, padded to 4352
    long b0 = (u - 1738752L) * 8;
#pragma unroll
    for (int e = 0; e < 8; ++e) {
      long gi = b0 + e;
      wpb2[gi] = (gi < 4095L) ? wpb[gi] * 1.4426950408889634f : 0.f;
    }
    return;
  } else return;
  const float4* s4 = (const float4*)(src + off * 8);
  float4 a = s4[0], b = s4[1];
  uint32_t p0 = (uint32_t)f2bf(a.x) | ((uint32_t)f2bf(a.y) << 16);
  uint32_t p1 = (uint32_t)f2bf(a.z) | ((uint32_t)f2bf(a.w) << 16);
  uint32_t p2 = (uint32_t)f2bf(b.x) | ((uint32_t)f2bf(b.y) << 16);
  uint32_t p3 = (uint32_t)f2bf(b.z) | ((uint32_t)f2bf(b.w) << 16);
  uint4 o = {p0, p1, p2, p3};
  *(uint4*)(dst + off * 8) = o;
}

// ---------------------------------------------------------------------------
// gemm_bt: C = (A @ W^T + bias) * scale.  A: 8192x512 bf16, W: 512x512 bf16.
// 128x128 tile, 4 waves, 32x32x16 MFMA, BK=32, global_load_lds staging.
// mode 0: bf16 out in (b,h,l,d); mode 1: fp32 out row-major.
// ---------------------------------------------------------------------------
__global__ __launch_bounds__(256) void gemm_bt(
    const u16* __restrict__ A, const u16* __restrict__ W, const float* __restrict__ bias,
    u16* __restrict__ obf, float* __restrict__ ofp, float scale, int mode) {
  __shared__ u16 Al[128 * 32];
  __shared__ u16 Bl[128 * 32];
  const int tid = threadIdx.x;
  const int lane = tid & 63, w = tid >> 6;
  const int wi = w >> 1, wj = w & 1;
  const int m0 = (blockIdx.x >> 2) * 128, n0 = (blockIdx.x & 3) * 128;

  f32x16 acc[2][2];
#pragma unroll
  for (int i = 0; i < 2; ++i)
#pragma unroll
    for (int j = 0; j < 2; ++j)
#pragma unroll
      for (int r = 0; r < 16; ++r) acc[i][j][r] = 0.f;

  for (int kb = 0; kb < 16; ++kb) {
#pragma unroll
    for (int c = 0; c < 2; ++c) {
      int s = c * 256 + w * 64 + lane;
      int r = s >> 2, ch = s & 3;
      int gch = ch ^ ((r >> 1) & 3);
      gl_lds16(A + (long)(m0 + r) * 512 + kb * 32 + gch * 8, (char*)Al + (c * 256 + w * 64) * 16);
      gl_lds16(W + (long)(n0 + r) * 512 + kb * 32 + gch * 8, (char*)Bl + (c * 256 + w * 64) * 16);
    }
    __syncthreads();
    bf16x8 af[2][2], bfr[2][2];
#pragma unroll
    for (int mt = 0; mt < 2; ++mt)
#pragma unroll
      for (int ks = 0; ks < 2; ++ks) {
        int r = 64 * wi + 32 * mt + (lane & 31);
        int ch = 2 * ks + (lane >> 5);
        af[mt][ks] = *(const bf16x8*)((char*)Al + (r * 4 + (ch ^ ((r >> 1) & 3))) * 16);
      }
#pragma unroll
    for (int nt = 0; nt < 2; ++nt)
#pragma unroll
      for (int ks = 0; ks < 2; ++ks) {
        int r = 64 * wj + 32 * nt + (lane & 31);
        int ch = 2 * ks + (lane >> 5);
        bfr[nt][ks] = *(const bf16x8*)((char*)Bl + (r * 4 + (ch ^ ((r >> 1) & 3))) * 16);
      }
#pragma unroll
    for (int mt = 0; mt < 2; ++mt)
#pragma unroll
      for (int nt = 0; nt < 2; ++nt)
#pragma unroll
        for (int ks = 0; ks < 2; ++ks)
          acc[mt][nt] = __builtin_amdgcn_mfma_f32_32x32x16_bf16(af[mt][ks], bfr[nt][ks],
                                                                acc[mt][nt], 0, 0, 0);
    __syncthreads();
  }
#pragma unroll
  for (int nt = 0; nt < 2; ++nt) {
    int n = n0 + 64 * wj + 32 * nt + (lane & 31);
    float bv = bias[n];
#pragma unroll
    for (int mt = 0; mt < 2; ++mt) {
#pragma unroll
      for (int r = 0; r < 16; ++r) {
        int row = m0 + 64 * wi + 32 * mt + (r & 3) + 8 * (r >> 2) + 4 * (lane >> 5);
        float val = (acc[mt][nt][r] + bv) * scale;
        if (mode == 0) {
          int b = row >> 11, l = row & 2047, h = n >> 6, d = n & 63;
          obf[(((long)(b * 8 + h)) * 2048 + l) * 64 + d] = f2bf(val);
        } else {
          ofp[(long)row * 512 + n] = val;
        }
      }
    }
  }
}

// ---------------------------------------------------------------------------
// Fused Q/K/V projection: 768 blocks (3 matrices x 256 tiles).
// q gets scale log2e/8 baked in (log2-unit logits downstream).
// ---------------------------------------------------------------------------
__global__ __launch_bounds__(256) void qkv_gemm(
    const u16* __restrict__ xq, const u16* __restrict__ xk, const u16* __restrict__ xv,
    const u16* __restrict__ wqp, const u16* __restrict__ wkp, const u16* __restrict__ wvp,
    const float* __restrict__ bq, const float* __restrict__ bk, const float* __restrict__ bv,
    u16* __restrict__ oq, u16* __restrict__ ok, u16* __restrict__ ov) {
  __shared__ u16 Al[128 * 32];
  __shared__ u16 Bl[128 * 32];
  const int mat = blockIdx.x >> 8;
  const int tile = blockIdx.x & 255;
  const u16* A = (mat == 0) ? xq : (mat == 1) ? xk : xv;
  const u16* W = (mat == 0) ? wqp : (mat == 1) ? wkp : wvp;
  const float* bias = (mat == 0) ? bq : (mat == 1) ? bk : bv;
  u16* obf = (mat == 0) ? oq : (mat == 1) ? ok : ov;
  const float scale = (mat == 0) ? 0.18033688f : 1.0f;  // log2e/8 for q

  const int tid = threadIdx.x;
  const int lane = tid & 63, w = tid >> 6;
  const int wi = w >> 1, wj = w & 1;
  const int m0 = (tile >> 2) * 128, n0 = (tile & 3) * 128;

  f32x16 acc[2][2];
#pragma unroll
  for (int i = 0; i < 2; ++i)
#pragma unroll
    for (int j = 0; j < 2; ++j)
#pragma unroll
      for (int r = 0; r < 16; ++r) acc[i][j][r] = 0.f;

  for (int kb = 0; kb < 16; ++kb) {
#pragma unroll
    for (int c = 0; c < 2; ++c) {
      int s = c * 256 + w * 64 + lane;
      int r = s >> 2, ch = s & 3;
      int gch = ch ^ ((r >> 1) & 3);
      gl_lds16(A + (long)(m0 + r) * 512 + kb * 32 + gch * 8, (char*)Al + (c * 256 + w * 64) * 16);
      gl_lds16(W + (long)(n0 + r) * 512 + kb * 32 + gch * 8, (char*)Bl + (c * 256 + w * 64) * 16);
    }
    __syncthreads();
    bf16x8 af[2][2], bfr[2][2];
#pragma unroll
    for (int mt = 0; mt < 2; ++mt)
#pragma unroll
      for (int ks = 0; ks < 2; ++ks) {
        int r = 64 * wi + 32 * mt + (lane & 31);
        int ch = 2 * ks + (lane >> 5);
        af[mt][ks] = *(const bf16x8*)((char*)Al + (r * 4 + (ch ^ ((r >> 1) & 3))) * 16);
      }
#pragma unroll
    for (int nt = 0; nt < 2; ++nt)
#pragma unroll
      for (int ks = 0; ks < 2; ++ks) {
        int r = 64 * wj + 32 * nt + (lane & 31);
        int ch = 2 * ks + (lane >> 5);
        bfr[nt][ks] = *(const bf16x8*)((char*)Bl + (r * 4 + (ch ^ ((r >> 1) & 3))) * 16);
      }
#pragma unroll
    for (int mt = 0; mt < 2; ++mt)
#pragma unroll
      for (int nt = 0; nt < 2; ++nt)
#pragma unroll
        for (int ks = 0; ks < 2; ++ks)
          acc[mt][nt] = __builtin_amdgcn_mfma_f32_32x32x16_bf16(af[mt][ks], bfr[nt][ks],
                                                                acc[mt][nt], 0, 0, 0);
    __syncthreads();
  }
#pragma unroll
  for (int nt = 0; nt < 2; ++nt) {
    int n = n0 + 64 * wj + 32 * nt + (lane & 31);
    float bvv = bias[n];
#pragma unroll
    for (int mt = 0; mt < 2; ++mt) {
#pragma unroll
      for (int r = 0; r < 16; ++r) {
        int row = m0 + 64 * wi + 32 * mt + (r & 3) + 8 * (r >> 2) + 4 * (lane >> 5);
        float val = (acc[mt][nt][r] + bvv) * scale;
        int b = row >> 11, l = row & 2047, h = n >> 6, d = n & 63;
        obf[(((long)(b * 8 + h)) * 2048 + l) * 64 + d] = f2bf(val);
      }
    }
  }
}

// ---------------------------------------------------------------------------
// pos_gemm (one half-batch pass): Pb[rowL][c] = q[rowL].wp[s0+c] + wpb2[s0+c],
// rowL in [0,4096) (local to the pass), c in [0,2112), s0 = 1984-(rowL&2047).
// Grid: 64 mtiles x 9 ntiles = 576 blocks, 4 waves x 64 cols; tiles covering
// c >= 2112 compute but skip the store (wp/wpb2 are zero-padded to 4352 rows
// so their reads stay in bounds).  K=64: fragments straight from global.
// ---------------------------------------------------------------------------
__global__ __launch_bounds__(256) void pos_gemm(
    const u16* __restrict__ q, const u16* __restrict__ wp, const float* __restrict__ wpb2,
    u16* __restrict__ Pb) {
  const int mtile = blockIdx.x / 9, ntile = blockIdx.x - mtile * 9;
  const int tid = threadIdx.x, lane = tid & 63, wv = tid >> 6;
  const int l31 = lane & 31, lh = lane >> 5;
  const int r0 = mtile * 64;
  const int s0 = 1984 - (r0 & 2047);
  const int c0 = ntile * 256 + wv * 64;

  bf16x8 af[2][4];
#pragma unroll
  for (int mt = 0; mt < 2; ++mt) {
    const u16* p = q + (long)(r0 + 32 * mt + l31) * 64 + lh * 8;
#pragma unroll
    for (int kk = 0; kk < 4; ++kk) af[mt][kk] = *(const bf16x8*)(p + kk * 16);
  }
#pragma unroll
  for (int nt = 0; nt < 2; ++nt) {
    const int cc = c0 + 32 * nt + l31;         // compressed col this lane owns
    const u16* bp = wp + (long)(s0 + cc) * 64 + lh * 8;
    bf16x8 bf[4];
#pragma unroll
    for (int kk = 0; kk < 4; ++kk) bf[kk] = *(const bf16x8*)(bp + kk * 16);
    f32x16 acc[2];
#pragma unroll
    for (int r = 0; r < 16; ++r) { acc[0][r] = 0.f; acc[1][r] = 0.f; }
#pragma unroll
    for (int mt = 0; mt < 2; ++mt)
#pragma unroll
      for (int kk = 0; kk < 4; ++kk)
        acc[mt] = __builtin_amdgcn_mfma_f32_32x32x16_bf16(af[mt][kk], bf[kk], acc[mt], 0, 0, 0);
    const float bv = wpb2[s0 + cc];
    if (cc < 2112) {
#pragma unroll
      for (int mt = 0; mt < 2; ++mt) {
#pragma unroll
        for (int r = 0; r < 16; ++r) {
          int row = r0 + 32 * mt + (r & 3) + 8 * (r >> 2) + 4 * lh;
          Pb[(long)row * 2112 + cc] = f2bf(acc[mt][r] + bv);
        }
      }
    }
  }
}

// ---------------------------------------------------------------------------
// Attention (one half-batch pass): one block per (bh_local, 64-row i-tile);
// 4 waves; NO barrier, NO LDS in the j-loop.  Per iter: 16 coalesced u16 pos
// gathers from Pb, 4 MFMA (K-frags prefetched 1 iter ahead), per element
// 1 add + 1 v_exp_f32.
// ---------------------------------------------------------------------------
__global__ __launch_bounds__(256, 4) void attn_kernel(
    const u16* __restrict__ qw, const u16* __restrict__ kw, const u16* __restrict__ vw,
    const u16* __restrict__ Pb, u16* __restrict__ outp, int bh_base) {
  __shared__ float sdiag[64];
  __shared__ float rssum[128];
  __shared__ float attw[64];

  const int tid = threadIdx.x, lane = tid & 63, w = tid >> 6;
  const int wi = w >> 1, wj = w & 1;
  const int it = blockIdx.x & 31, bhl = blockIdx.x >> 5;
  const int bh = bh_base + bhl;
  const int i0 = it * 64;
  const int l31 = lane & 31, lh = lane >> 5;
  const u16* qb = qw + (long)bh * 131072;
  const u16* kb = kw + (long)bh * 131072;
  const u16* vb = vw + (long)bh * 131072;

  // A-frags: Q rows i0+32wi+l31, full K=64 (pre-scaled by log2e/8)
  bf16x8 aq[4];
  {
    const u16* p = qb + (long)(i0 + 32 * wi + l31) * 64 + lh * 8;
#pragma unroll
    for (int kk = 0; kk < 4; ++kk) aq[kk] = *(const bf16x8*)(p + kk * 16);
  }
  // K fragment prefetch (jt=0)
  const int koff = (32 * wj + l31) * 64 + lh * 8;
  bf16x8 kf[4];
  {
    const u16* p = kb + koff;
#pragma unroll
    for (int kk = 0; kk < 4; ++kk) kf[kk] = *(const bf16x8*)(p + kk * 16);
  }
  // pos gather: Pb[rowL][c], rowL = bhl*2048+i0+32wi+lrr+4lh,
  // c = 63 + (64jt+32wj+l31) - (32wi+lrr+4lh); idx = base + lrr*2111.
  uint32_t base = (uint32_t)(bhl * 2048 + i0 + 32 * wi + 4 * lh) * 2112u +
                  (uint32_t)(63 + 32 * wj + l31 - 32 * wi - 4 * lh);
  float rsum[16];
#pragma unroll
  for (int r = 0; r < 16; ++r) rsum[r] = 0.f;

  for (int jt = 0; jt < 32; ++jt) {
    // pos gathers (issued first; consumed after the MFMAs)
    uint32_t pvv[16];
#pragma unroll
    for (int r = 0; r < 16; ++r) {
      const uint32_t lrr = (uint32_t)((r & 3) + 8 * (r >> 2));
      pvv[r] = (uint32_t)Pb[base + lrr * 2111u];
    }
    // prefetch next K tile
    bf16x8 kn[4];
    {
      const u16* p = kb + ((jt + 1) & 31) * 4096 + koff;
#pragma unroll
      for (int kk = 0; kk < 4; ++kk) kn[kk] = *(const bf16x8*)(p + kk * 16);
    }
    // scores
    f32x16 accS;
#pragma unroll
    for (int r = 0; r < 16; ++r) accS[r] = 0.f;
#pragma unroll
    for (int kk = 0; kk < 4; ++kk)
      accS = __builtin_amdgcn_mfma_f32_32x32x16_bf16(aq[kk], kf[kk], accS, 0, 0, 0);
    // combine: s = qk + pos (log2 units), accumulate 2^s
#pragma unroll
    for (int r = 0; r < 16; ++r) {
      float p = __uint_as_float(pvv[r] << 16);
      float s = accS[r] + p;
      rsum[r] += __builtin_amdgcn_exp2f(s);
    }
    // diagonal logit capture (uniform branch, one jt per wave pair)
    if (jt == it && wi == wj) {
#pragma unroll
      for (int r = 0; r < 16; ++r) {
        const int lrr = (r & 3) + 8 * (r >> 2);
        if (lrr + 4 * lh == l31) {
          float p = __uint_as_float(pvv[r] << 16);
          sdiag[32 * wi + l31] = accS[r] + p;
        }
      }
    }
#pragma unroll
    for (int kk = 0; kk < 4; ++kk) kf[kk] = kn[kk];
    base += 64u;
  }

  // reduce row partials across the 32 lanes sharing each row
#pragma unroll
  for (int r = 0; r < 16; ++r) {
    float v = rsum[r];
    v += __shfl_xor(v, 1);
    v += __shfl_xor(v, 2);
    v += __shfl_xor(v, 4);
    v += __shfl_xor(v, 8);
    v += __shfl_xor(v, 16);
    rsum[r] = v;
  }
  if (l31 == 0) {
#pragma unroll
    for (int r = 0; r < 16; ++r) {
      int lr = (r & 3) + 8 * (r >> 2) + 4 * lh;
      rssum[(32 * wi + lr) * 2 + wj] = rsum[r];
    }
  }
  __syncthreads();
  if (tid < 64) {
    float S = rssum[2 * tid] + rssum[2 * tid + 1];
    attw[tid] = __builtin_amdgcn_exp2f(sdiag[tid]) / S;
  }
  __syncthreads();
  // out_pre[b*2048 + i][h*64 + d] = diag * v   (bf16)
  {
    int r = tid >> 2, dd = (tid & 3) * 16;
    float a = attw[r];
    int b = bh >> 3, h = bh & 7;
    const u16* vp = vb + (long)(i0 + r) * 64 + dd;
    u16* op = outp + ((long)(b * 2048 + i0 + r)) * 512 + h * 64 + dd;
    uint4 v0 = *(const uint4*)vp;
    uint4 v1 = *(const uint4*)(vp + 8);
    uint32_t vin[8] = {v0.x, v0.y, v0.z, v0.w, v1.x, v1.y, v1.z, v1.w};
    uint32_t vout[8];
#pragma unroll
    for (int e = 0; e < 8; ++e) {
      float lo = bf2f((u16)(vin[e] & 0xffffu)) * a;
      float hi = bf2f((u16)(vin[e] >> 16)) * a;
      vout[e] = (uint32_t)f2bf(lo) | ((uint32_t)f2bf(hi) << 16);
    }
    uint4 o0 = {vout[0], vout[1], vout[2], vout[3]};
    uint4 o1 = {vout[4], vout[5], vout[6], vout[7]};
    *(uint4*)op = o0;
    *(uint4*)(op + 8) = o1;
  }
}

// ---------------------------------------------------------------------------
extern "C" void kernel_launch(void* const* d_in, const int* in_sizes, int n_in,
                              void* d_out, int out_size, void* d_ws, size_t ws_size,
                              hipStream_t stream) {
  (void)in_sizes; (void)n_in; (void)out_size; (void)ws_size;
  const float* q_in = (const float*)d_in[0];
  const float* k_in = (const float*)d_in[1];
  const float* v_in = (const float*)d_in[2];
  const float* Wq_w = (const float*)d_in[3];
  const float* Wq_b = (const float*)d_in[4];
  const float* Wk_w = (const float*)d_in[5];
  const float* Wk_b = (const float*)d_in[6];
  const float* Wv_w = (const float*)d_in[7];
  const float* Wv_b = (const float*)d_in[8];
  const float* Wo_w = (const float*)d_in[9];
  const float* Wo_b = (const float*)d_in[10];
  const float* Wp_w = (const float*)d_in[11];
  const float* Wp_b = (const float*)d_in[12];

  // Workspace layout (peak 53,528,576 B; Round-2's proven 61.3 MB is the cap):
  //   persistent: wq..wo 2 MB | wp 0.55 MB | wpb2 17 KB | q/k/v_ws 24 MB |
  //   opre 8 MB | Pb 17.3 MB (per-pass, bh-half)
  //   transients xq/xk/xv (24 MB) alias opre+Pb (dead before pos_gemm).
  char* ws = (char*)d_ws;
  u16*   wq    = (u16*)(ws + 0);
  u16*   wk    = (u16*)(ws + 524288);
  u16*   wv    = (u16*)(ws + 1048576);
  u16*   wo    = (u16*)(ws + 1572864);
  u16*   wp    = (u16*)(ws + 2097152);    // 4352x64 bf16 = 557,056
  float* wpb2  = (float*)(ws + 2654208);  // 4352 fp32 -> ends 2,671,616
  u16*   q_ws  = (u16*)(ws + 2672640);    // 8 MB (b,h,l,d), log2e/8-scaled
  u16*   k_ws  = (u16*)(ws + 11061248);   // 8 MB
  u16*   v_ws  = (u16*)(ws + 19449856);   // 8 MB
  u16*   opre  = (u16*)(ws + 27838464);   // 8 MB (b*l, h*d)
  u16*   Pb    = (u16*)(ws + 36227072);   // 4096x2112 bf16 = 17,301,504 -> 53,528,576
  u16*   xq    = (u16*)(ws + 27838464);   // aliases opre (dead by attn)
  u16*   xk    = (u16*)(ws + 36227072);   // aliases Pb
  u16*   xv    = (u16*)(ws + 44615680);   // ends 53,004,288

  prep_kernel<<<6795, 256, 0, stream>>>(q_in, k_in, v_in, Wq_w, Wk_w, Wv_w, Wo_w, Wp_w, Wp_b,
                                        xq, xk, xv, wq, wk, wv, wo, wp, wpb2);
  qkv_gemm<<<768, 256, 0, stream>>>(xq, xk, xv, wq, wk, wv, Wq_b, Wk_b, Wv_b,
                                    q_ws, k_ws, v_ws);
  // two half-batch passes: bh 0..15, then 16..31 (Pb reused)
  for (int p = 0; p < 2; ++p) {
    pos_gemm<<<576, 256, 0, stream>>>(q_ws + (long)p * 16 * 131072, wp, wpb2, Pb);
    attn_kernel<<<512, 256, 0, stream>>>(q_ws, k_ws, v_ws, Pb, opre, p * 16);
  }
  gemm_bt<<<256, 256, 0, stream>>>(opre, wo, Wo_b, nullptr, (float*)d_out, 1.0f, 1);
}